// Round 5
// baseline (732.668 us; speedup 1.0000x reference)
//
#include <hip/hip_runtime.h>

#define N_NODES 50000
#define N_EDGES 1600000

// Workspace element offsets (4-byte units). Peak ~70.8 MB.
#define O_CNTO 0         // int[50000]   out-degree counts
#define O_HEAD 50000     // int[50000]   linked-list heads (by dst), -1 = empty
#define O_NEXT 100000    // int[1.6M]    next edge index in dst-chain
#define O_HB   1700000   // uint[3.2M]   bf16x2 h*norm_out
#define O_AGG  4900000   // f32[6.4M]    agg; overwritten by Q in-place
#define O_KV   11300000  // uint[6.4M]   interleaved bf16 K/V rows (512 B/node)

typedef unsigned int uint;

__device__ __forceinline__ uint f2bf2(float a, float b) {
    uint ua = __float_as_uint(a); ua = (ua + 0x7fffu + ((ua >> 16) & 1u)) >> 16;
    uint ub = __float_as_uint(b); ub = (ub + 0x7fffu + ((ub >> 16) & 1u)) >> 16;
    return ua | (ub << 16);
}

// Build dst-linked-list + out-degree histogram in one pass.
__global__ __launch_bounds__(256) void k_links(const int* __restrict__ src,
                                               const int* __restrict__ dst,
                                               int* head, int* next, int* cnt_out) {
    int e = blockIdx.x * 256 + threadIdx.x;
    if (e < N_EDGES) {
        int d = dst[e], s = src[e];
        next[e] = atomicExch(&head[d], e);
        atomicAdd(&cnt_out[s], 1);
    }
}

// hb[n][j] = bf16(h[n][j] * rsqrt(max(deg_out,1))); one uint (2 bf16) per thread
__global__ __launch_bounds__(256) void k_hb(const float* __restrict__ h,
                                            const int* __restrict__ cnt_out,
                                            uint* __restrict__ hb) {
    int idx = blockIdx.x * 256 + threadIdx.x;   // [0, N*64)
    if (idx < N_NODES * 64) {
        int n = idx >> 6;
        float no = rsqrtf(fmaxf((float)cnt_out[n], 1.0f));
        float2 hv = *(const float2*)(h + ((size_t)idx << 1));
        hb[idx] = f2bf2(hv.x * no, hv.y * no);
    }
}

// agg[n] = rsqrt(max(deg_in,1)) * sum_{e: dst=n} hb[src_e]
// one wave per TWO nodes (interleaved chains for MLP); lane owns dim pair `lane`.
__global__ __launch_bounds__(256) void k_agg_list(
    const int* __restrict__ head, const int* __restrict__ next,
    const int* __restrict__ src, const uint* __restrict__ hb,
    float* __restrict__ agg)
{
    int waveId = (blockIdx.x << 2) + (threadIdx.x >> 6);   // 0..24999
    int lane = threadIdx.x & 63;
    int nA = waveId << 1, nB = nA + 1;
    int eA = head[nA], eB = head[nB];
    float axA = 0.f, ayA = 0.f, axB = 0.f, ayB = 0.f;
    int cA = 0, cB = 0;
    while (eA >= 0 || eB >= 0) {
        int sA = 0, sB = 0, nxA = -1, nxB = -1;
        uint uA = 0, uB = 0;
        bool pA = eA >= 0, pB = eB >= 0;
        if (pA) { sA = src[eA]; nxA = next[eA]; }
        if (pB) { sB = src[eB]; nxB = next[eB]; }
        if (pA) uA = hb[((size_t)sA << 6) + lane];
        if (pB) uB = hb[((size_t)sB << 6) + lane];
        if (pA) {
            axA += __uint_as_float(uA << 16);
            ayA += __uint_as_float(uA & 0xffff0000u);
            ++cA; eA = nxA;
        }
        if (pB) {
            axB += __uint_as_float(uB << 16);
            ayB += __uint_as_float(uB & 0xffff0000u);
            ++cB; eB = nxB;
        }
    }
    float niA = rsqrtf(fmaxf((float)cA, 1.0f));
    float niB = rsqrtf(fmaxf((float)cB, 1.0f));
    float2 oA; oA.x = axA * niA; oA.y = ayA * niA;
    float2 oB; oB.x = axB * niB; oB.y = ayB * niB;
    *(float2*)(agg + ((size_t)nA << 7) + (lane << 1)) = oA;
    *(float2*)(agg + ((size_t)nB << 7) + (lane << 1)) = oB;
}

// K,V GEMM -> interleaved bf16 KV buffer.
// KV row = 128 uints: uint 2j = K dims [2j,2j+1], uint 2j+1 = V dims [2j,2j+1]
__global__ __launch_bounds__(128) void k_kv(
    const float* __restrict__ agg,
    const float* __restrict__ WK, const float* __restrict__ bK,
    const float* __restrict__ WV, const float* __restrict__ bV,
    uint* __restrict__ kv)
{
    const int isV = blockIdx.y;
    const float* W    = isV ? WV : WK;
    const float* bias = isV ? bV : bK;
    const int row0 = blockIdx.x * 32;
    const int col0 = blockIdx.z * 64;

    __shared__ float sW[128][64];
    __shared__ float sA[128][36];

    const int t = threadIdx.x;
    {
        const float* Wp = W + col0;
        for (int i = t; i < 128 * 16; i += 128) {
            int k = i >> 4, c4 = (i & 15) << 2;
            *(float4*)(&sW[k][c4]) = *(const float4*)(Wp + k * 128 + c4);
        }
        for (int i = t; i < 32 * 32; i += 128) {
            int r = i >> 5, k4 = (i & 31) << 2;
            int row = row0 + r;
            float4 a = make_float4(0.f, 0.f, 0.f, 0.f);
            if (row < N_NODES) a = *(const float4*)(agg + (size_t)row * 128 + k4);
            sA[k4 + 0][r] = a.x; sA[k4 + 1][r] = a.y;
            sA[k4 + 2][r] = a.z; sA[k4 + 3][r] = a.w;
        }
    }
    __syncthreads();

    const int rq = (t & 7) << 2;
    const int cq = (t >> 3) << 2;
    float acc[4][4] = {};
    for (int k = 0; k < 128; ++k) {
        float4 a = *(const float4*)(&sA[k][rq]);
        float4 w = *(const float4*)(&sW[k][cq]);
        acc[0][0] += a.x * w.x; acc[0][1] += a.x * w.y; acc[0][2] += a.x * w.z; acc[0][3] += a.x * w.w;
        acc[1][0] += a.y * w.x; acc[1][1] += a.y * w.y; acc[1][2] += a.y * w.z; acc[1][3] += a.y * w.w;
        acc[2][0] += a.z * w.x; acc[2][1] += a.z * w.y; acc[2][2] += a.z * w.z; acc[2][3] += a.z * w.w;
        acc[3][0] += a.w * w.x; acc[3][1] += a.w * w.y; acc[3][2] += a.w * w.z; acc[3][3] += a.w * w.w;
    }

    float4 bv = *(const float4*)(bias + col0 + cq);
    const int c = col0 + cq;
    for (int i = 0; i < 4; ++i) {
        int row = row0 + rq + i;
        if (row < N_NODES) {
            float ox = fmaxf(acc[i][0] + bv.x, 0.f);
            float oy = fmaxf(acc[i][1] + bv.y, 0.f);
            float oz = fmaxf(acc[i][2] + bv.z, 0.f);
            float ow = fmaxf(acc[i][3] + bv.w, 0.f);
            uint* o = kv + ((size_t)row << 7) + c + isV;
            o[0] = f2bf2(ox, oy);
            o[2] = f2bf2(oz, ow);
        }
    }
}

// Q GEMM in-place over agg
__global__ __launch_bounds__(256) void k_q_inplace(
    float* __restrict__ agg, const float* __restrict__ WQ,
    const float* __restrict__ bQ)
{
    const int row0 = blockIdx.x * 32;
    __shared__ float sA[128][36];
    __shared__ float sW[32][128];

    const int t = threadIdx.x;
    for (int i = t; i < 32 * 32; i += 256) {
        int r = i >> 5, k4 = (i & 31) << 2;
        int row = row0 + r;
        float4 a = make_float4(0.f, 0.f, 0.f, 0.f);
        if (row < N_NODES) a = *(const float4*)(agg + (size_t)row * 128 + k4);
        sA[k4 + 0][r] = a.x; sA[k4 + 1][r] = a.y;
        sA[k4 + 2][r] = a.z; sA[k4 + 3][r] = a.w;
    }

    const int rq = (t & 7) << 2;
    const int cq = (t >> 3) << 2;
    float acc[4][4] = {};

    for (int kc = 0; kc < 128; kc += 32) {
        __syncthreads();
        for (int i = t; i < 1024; i += 256) {
            int k = i >> 5, c4 = (i & 31) << 2;
            *(float4*)(&sW[k][c4]) = *(const float4*)(WQ + (size_t)(kc + k) * 128 + c4);
        }
        __syncthreads();
        for (int kk = 0; kk < 32; ++kk) {
            float4 a = *(const float4*)(&sA[kc + kk][rq]);
            float4 w = *(const float4*)(&sW[kk][cq]);
            acc[0][0] += a.x * w.x; acc[0][1] += a.x * w.y; acc[0][2] += a.x * w.z; acc[0][3] += a.x * w.w;
            acc[1][0] += a.y * w.x; acc[1][1] += a.y * w.y; acc[1][2] += a.y * w.z; acc[1][3] += a.y * w.w;
            acc[2][0] += a.z * w.x; acc[2][1] += a.z * w.y; acc[2][2] += a.z * w.z; acc[2][3] += a.z * w.w;
            acc[3][0] += a.w * w.x; acc[3][1] += a.w * w.y; acc[3][2] += a.w * w.z; acc[3][3] += a.w * w.w;
        }
    }

    float4 bv = *(const float4*)(bQ + cq);
    for (int i = 0; i < 4; ++i) {
        int row = row0 + rq + i;
        if (row < N_NODES) {
            float4 o;
            o.x = fmaxf(acc[i][0] + bv.x, 0.f);
            o.y = fmaxf(acc[i][1] + bv.y, 0.f);
            o.z = fmaxf(acc[i][2] + bv.z, 0.f);
            o.w = fmaxf(acc[i][3] + bv.w, 0.f);
            *(float4*)(agg + (size_t)row * 128 + cq) = o;
        }
    }
}

__device__ __forceinline__ void attn_step(uint2 kvp, float qx, float qy,
                                          float& ax, float& ay, float& zacc) {
    float p = __uint_as_float(kvp.x << 16) * qx
            + __uint_as_float(kvp.x & 0xffff0000u) * qy;
    p += __shfl_xor(p, 1);
    p += __shfl_xor(p, 2);
    p += __shfl_xor(p, 4);
    float sc = __expf(fminf(fmaxf(p * 0.25f, -10.f), 10.f));
    ax += __uint_as_float(kvp.y << 16) * sc;
    ay += __uint_as_float(kvp.y & 0xffff0000u) * sc;
    zacc += sc;
}

// Attention gather over interleaved KV via linked-list chase; 2 nodes per wave.
__global__ __launch_bounds__(256) void k_attn_list(
    const int* __restrict__ head, const int* __restrict__ next,
    const int* __restrict__ src,
    const float* __restrict__ Q, const uint* __restrict__ kv,
    float* __restrict__ out)
{
    int waveId = (blockIdx.x << 2) + (threadIdx.x >> 6);
    int lane = threadIdx.x & 63;
    int nA = waveId << 1, nB = nA + 1;

    float2 qA = *(const float2*)(Q + ((size_t)nA << 7) + (lane << 1));
    float2 qB = *(const float2*)(Q + ((size_t)nB << 7) + (lane << 1));
    int eA = head[nA], eB = head[nB];
    float axA = 0.f, ayA = 0.f, zA = 0.f;
    float axB = 0.f, ayB = 0.f, zB = 0.f;

    while (eA >= 0 || eB >= 0) {
        int sA = 0, sB = 0, nxA = -1, nxB = -1;
        uint2 pAv = make_uint2(0u, 0u), pBv = make_uint2(0u, 0u);
        bool pA = eA >= 0, pB = eB >= 0;
        if (pA) { sA = src[eA]; nxA = next[eA]; }
        if (pB) { sB = src[eB]; nxB = next[eB]; }
        if (pA) pAv = *(const uint2*)(kv + ((size_t)sA << 7) + (lane << 1));
        if (pB) pBv = *(const uint2*)(kv + ((size_t)sB << 7) + (lane << 1));
        if (pA) { attn_step(pAv, qA.x, qA.y, axA, ayA, zA); eA = nxA; }
        if (pB) { attn_step(pBv, qB.x, qB.y, axB, ayB, zB); eB = nxB; }
    }

    float invA = 1.0f / (zA + 1e-6f);
    float invB = 1.0f / (zB + 1e-6f);
    float2 oA; oA.x = axA * invA; oA.y = ayA * invA;
    float2 oB; oB.x = axB * invB; oB.y = ayB * invB;
    *(float2*)(out + ((size_t)nA << 7) + (lane << 1)) = oA;
    *(float2*)(out + ((size_t)nB << 7) + (lane << 1)) = oB;
}

extern "C" void kernel_launch(void* const* d_in, const int* in_sizes, int n_in,
                              void* d_out, int out_size, void* d_ws, size_t ws_size,
                              hipStream_t stream) {
    const float* h   = (const float*)d_in[0];
    const float* WQ  = (const float*)d_in[1];
    const float* bQ  = (const float*)d_in[2];
    const float* WK  = (const float*)d_in[3];
    const float* bK  = (const float*)d_in[4];
    const float* WV  = (const float*)d_in[5];
    const float* bV  = (const float*)d_in[6];
    const int*   src = (const int*)d_in[7];
    const int*   dst = (const int*)d_in[8];
    float* out = (float*)d_out;
    float* ws  = (float*)d_ws;
    int*   wsi = (int*)d_ws;

    int*   cnt_out = wsi + O_CNTO;
    int*   head    = wsi + O_HEAD;
    int*   next    = wsi + O_NEXT;
    uint*  hb      = (uint*)(ws + O_HB);
    float* agg     = ws + O_AGG;     // becomes Q in-place
    uint*  kv      = (uint*)(ws + O_KV);

    hipMemsetAsync(cnt_out, 0, N_NODES * sizeof(int), stream);
    hipMemsetAsync(head, 0xFF, N_NODES * sizeof(int), stream);   // head = -1

    k_links<<<N_EDGES / 256, 256, 0, stream>>>(src, dst, head, next, cnt_out);
    k_hb<<<(N_NODES * 64 + 255) / 256, 256, 0, stream>>>(h, cnt_out, hb);

    k_agg_list<<<N_NODES / 8, 256, 0, stream>>>(head, next, src, hb, agg);

    dim3 g_kv((N_NODES + 31) / 32, 2, 2);
    k_kv<<<g_kv, 128, 0, stream>>>(agg, WK, bK, WV, bV, kv);
    k_q_inplace<<<(N_NODES + 31) / 32, 256, 0, stream>>>(agg, WQ, bQ);

    k_attn_list<<<N_NODES / 8, 256, 0, stream>>>(head, next, src, agg, kv, out);
}

// Round 6
// 560.254 us; speedup vs baseline: 1.3077x; 1.3077x over previous
//
#include <hip/hip_runtime.h>

#define N_NODES 50000
#define N_EDGES 1600000
#define CAP 64            // bucket capacity per node; Poisson(32) tail @64 ~ 1e-7
#define OVF_CAP 8192

// Workspace element offsets (4-byte units). Peak ~77.2 MB.
#define O_CNTO   0         // int[50000]  out-degree
#define O_CNTI   50000     // int[50000]  in-degree (also bucket fill)
#define O_OVFN   100000    // int[1]      overflow count
#define O_OVF    100002    // int2[8192]  overflow (dst,src) pairs
#define O_BUCKET 120000    // int[50000*64] src per slot
#define O_HB     3320000   // uint[3.2M]  bf16x2 h*norm_out
#define O_AGG    6520000   // f32[6.4M]   agg; overwritten by Q in-place
#define O_KV     12920000  // uint[6.4M]  interleaved bf16 K/V rows (512 B/node)

typedef unsigned int uint;

__device__ __forceinline__ uint f2bf2(float a, float b) {
    uint ua = __float_as_uint(a); ua = (ua + 0x7fffu + ((ua >> 16) & 1u)) >> 16;
    uint ub = __float_as_uint(b); ub = (ub + 0x7fffu + ((ub >> 16) & 1u)) >> 16;
    return ua | (ub << 16);
}

// One-pass build: out-degree histogram + dst-buckets (with overflow safety net).
__global__ __launch_bounds__(256) void k_build(const int* __restrict__ src,
                                               const int* __restrict__ dst,
                                               int* cnt_out, int* cnt_in,
                                               int* __restrict__ bucket,
                                               int* ovf_n, int2* __restrict__ ovf) {
    int e = blockIdx.x * 256 + threadIdx.x;
    if (e < N_EDGES) {
        int s = src[e], d = dst[e];
        atomicAdd(&cnt_out[s], 1);
        int pos = atomicAdd(&cnt_in[d], 1);
        if (pos < CAP) {
            bucket[(d << 6) + pos] = s;
        } else {
            int o = atomicAdd(ovf_n, 1);
            if (o < OVF_CAP) ovf[o] = make_int2(d, s);
        }
    }
}

// hb[n][j] = bf16(h[n][j] * rsqrt(max(deg_out,1))); one uint (2 bf16) per thread
__global__ __launch_bounds__(256) void k_hb(const float* __restrict__ h,
                                            const int* __restrict__ cnt_out,
                                            uint* __restrict__ hb) {
    int idx = blockIdx.x * 256 + threadIdx.x;   // [0, N*64)
    if (idx < N_NODES * 64) {
        int n = idx >> 6;
        float no = rsqrtf(fmaxf((float)cnt_out[n], 1.0f));
        float2 hv = *(const float2*)(h + ((size_t)idx << 1));
        hb[idx] = f2bf2(hv.x * no, hv.y * no);
    }
}

// agg[n] = rsqrt(max(deg_in,1)) * sum_{slots of n} hb[s]
// one wave per node, 4 nodes/block; lane owns dim pair `lane`; unrolled x4
__global__ __launch_bounds__(256) void k_agg(
    const int* __restrict__ cnt_in, const int* __restrict__ bucket,
    const int* __restrict__ ovf_n, const int2* __restrict__ ovf,
    const uint* __restrict__ hb, float* __restrict__ agg)
{
    int n = blockIdx.x * 4 + (threadIdx.x >> 6);
    int lane = threadIdx.x & 63;
    int cnt = cnt_in[n];
    int m = min(cnt, CAP);
    const int* b = bucket + ((size_t)n << 6);
    float ax = 0.f, ay = 0.f;
    int i = 0;
    for (; i + 4 <= m; i += 4) {
        int s0 = b[i], s1 = b[i + 1], s2 = b[i + 2], s3 = b[i + 3];
        uint u0 = hb[((size_t)s0 << 6) + lane];
        uint u1 = hb[((size_t)s1 << 6) + lane];
        uint u2 = hb[((size_t)s2 << 6) + lane];
        uint u3 = hb[((size_t)s3 << 6) + lane];
        ax += __uint_as_float(u0 << 16) + __uint_as_float(u1 << 16)
            + __uint_as_float(u2 << 16) + __uint_as_float(u3 << 16);
        ay += __uint_as_float(u0 & 0xffff0000u) + __uint_as_float(u1 & 0xffff0000u)
            + __uint_as_float(u2 & 0xffff0000u) + __uint_as_float(u3 & 0xffff0000u);
    }
    for (; i < m; ++i) {
        int s = b[i];
        uint u = hb[((size_t)s << 6) + lane];
        ax += __uint_as_float(u << 16);
        ay += __uint_as_float(u & 0xffff0000u);
    }
    if (cnt > CAP) {                       // statistically never; correctness net
        int on = min(*ovf_n, OVF_CAP);
        for (int j = 0; j < on; ++j) {
            int2 p = ovf[j];
            if (p.x == n) {
                uint u = hb[((size_t)p.y << 6) + lane];
                ax += __uint_as_float(u << 16);
                ay += __uint_as_float(u & 0xffff0000u);
            }
        }
    }
    float ni = rsqrtf(fmaxf((float)cnt, 1.0f));
    float2 o; o.x = ax * ni; o.y = ay * ni;
    *(float2*)(agg + ((size_t)n << 7) + (lane << 1)) = o;
}

// K,V GEMM -> interleaved bf16 KV buffer.
// KV row = 128 uints: uint 2j = K dims [2j,2j+1], uint 2j+1 = V dims [2j,2j+1]
__global__ __launch_bounds__(128) void k_kv(
    const float* __restrict__ agg,
    const float* __restrict__ WK, const float* __restrict__ bK,
    const float* __restrict__ WV, const float* __restrict__ bV,
    uint* __restrict__ kv)
{
    const int isV = blockIdx.y;
    const float* W    = isV ? WV : WK;
    const float* bias = isV ? bV : bK;
    const int row0 = blockIdx.x * 32;
    const int col0 = blockIdx.z * 64;

    __shared__ float sW[128][64];
    __shared__ float sA[128][36];

    const int t = threadIdx.x;
    {
        const float* Wp = W + col0;
        for (int i = t; i < 128 * 16; i += 128) {
            int k = i >> 4, c4 = (i & 15) << 2;
            *(float4*)(&sW[k][c4]) = *(const float4*)(Wp + k * 128 + c4);
        }
        for (int i = t; i < 32 * 32; i += 128) {
            int r = i >> 5, k4 = (i & 31) << 2;
            int row = row0 + r;
            float4 a = make_float4(0.f, 0.f, 0.f, 0.f);
            if (row < N_NODES) a = *(const float4*)(agg + (size_t)row * 128 + k4);
            sA[k4 + 0][r] = a.x; sA[k4 + 1][r] = a.y;
            sA[k4 + 2][r] = a.z; sA[k4 + 3][r] = a.w;
        }
    }
    __syncthreads();

    const int rq = (t & 7) << 2;
    const int cq = (t >> 3) << 2;
    float acc[4][4] = {};
    for (int k = 0; k < 128; ++k) {
        float4 a = *(const float4*)(&sA[k][rq]);
        float4 w = *(const float4*)(&sW[k][cq]);
        acc[0][0] += a.x * w.x; acc[0][1] += a.x * w.y; acc[0][2] += a.x * w.z; acc[0][3] += a.x * w.w;
        acc[1][0] += a.y * w.x; acc[1][1] += a.y * w.y; acc[1][2] += a.y * w.z; acc[1][3] += a.y * w.w;
        acc[2][0] += a.z * w.x; acc[2][1] += a.z * w.y; acc[2][2] += a.z * w.z; acc[2][3] += a.z * w.w;
        acc[3][0] += a.w * w.x; acc[3][1] += a.w * w.y; acc[3][2] += a.w * w.z; acc[3][3] += a.w * w.w;
    }

    float4 bv = *(const float4*)(bias + col0 + cq);
    const int c = col0 + cq;
    for (int i = 0; i < 4; ++i) {
        int row = row0 + rq + i;
        if (row < N_NODES) {
            float ox = fmaxf(acc[i][0] + bv.x, 0.f);
            float oy = fmaxf(acc[i][1] + bv.y, 0.f);
            float oz = fmaxf(acc[i][2] + bv.z, 0.f);
            float ow = fmaxf(acc[i][3] + bv.w, 0.f);
            uint* o = kv + ((size_t)row << 7) + c + isV;
            o[0] = f2bf2(ox, oy);
            o[2] = f2bf2(oz, ow);
        }
    }
}

// Q GEMM in-place over agg
__global__ __launch_bounds__(256) void k_q_inplace(
    float* __restrict__ agg, const float* __restrict__ WQ,
    const float* __restrict__ bQ)
{
    const int row0 = blockIdx.x * 32;
    __shared__ float sA[128][36];
    __shared__ float sW[32][128];

    const int t = threadIdx.x;
    for (int i = t; i < 32 * 32; i += 256) {
        int r = i >> 5, k4 = (i & 31) << 2;
        int row = row0 + r;
        float4 a = make_float4(0.f, 0.f, 0.f, 0.f);
        if (row < N_NODES) a = *(const float4*)(agg + (size_t)row * 128 + k4);
        sA[k4 + 0][r] = a.x; sA[k4 + 1][r] = a.y;
        sA[k4 + 2][r] = a.z; sA[k4 + 3][r] = a.w;
    }

    const int rq = (t & 7) << 2;
    const int cq = (t >> 3) << 2;
    float acc[4][4] = {};

    for (int kc = 0; kc < 128; kc += 32) {
        __syncthreads();
        for (int i = t; i < 1024; i += 256) {
            int k = i >> 5, c4 = (i & 31) << 2;
            *(float4*)(&sW[k][c4]) = *(const float4*)(WQ + (size_t)(kc + k) * 128 + c4);
        }
        __syncthreads();
        for (int kk = 0; kk < 32; ++kk) {
            float4 a = *(const float4*)(&sA[kc + kk][rq]);
            float4 w = *(const float4*)(&sW[kk][cq]);
            acc[0][0] += a.x * w.x; acc[0][1] += a.x * w.y; acc[0][2] += a.x * w.z; acc[0][3] += a.x * w.w;
            acc[1][0] += a.y * w.x; acc[1][1] += a.y * w.y; acc[1][2] += a.y * w.z; acc[1][3] += a.y * w.w;
            acc[2][0] += a.z * w.x; acc[2][1] += a.z * w.y; acc[2][2] += a.z * w.z; acc[2][3] += a.z * w.w;
            acc[3][0] += a.w * w.x; acc[3][1] += a.w * w.y; acc[3][2] += a.w * w.z; acc[3][3] += a.w * w.w;
        }
    }

    float4 bv = *(const float4*)(bQ + cq);
    for (int i = 0; i < 4; ++i) {
        int row = row0 + rq + i;
        if (row < N_NODES) {
            float4 o;
            o.x = fmaxf(acc[i][0] + bv.x, 0.f);
            o.y = fmaxf(acc[i][1] + bv.y, 0.f);
            o.z = fmaxf(acc[i][2] + bv.z, 0.f);
            o.w = fmaxf(acc[i][3] + bv.w, 0.f);
            *(float4*)(agg + (size_t)row * 128 + cq) = o;
        }
    }
}

__device__ __forceinline__ void attn_step(uint2 kvp, float qx, float qy,
                                          float& ax, float& ay, float& zacc) {
    float p = __uint_as_float(kvp.x << 16) * qx
            + __uint_as_float(kvp.x & 0xffff0000u) * qy;
    p += __shfl_xor(p, 1);
    p += __shfl_xor(p, 2);
    p += __shfl_xor(p, 4);
    float sc = __expf(fminf(fmaxf(p * 0.25f, -10.f), 10.f));
    ax += __uint_as_float(kvp.y << 16) * sc;
    ay += __uint_as_float(kvp.y & 0xffff0000u) * sc;
    zacc += sc;
}

// Attention gather over interleaved KV from buckets; one wave per node; unroll x4
__global__ __launch_bounds__(256) void k_attn(
    const int* __restrict__ cnt_in, const int* __restrict__ bucket,
    const int* __restrict__ ovf_n, const int2* __restrict__ ovf,
    const float* __restrict__ Q, const uint* __restrict__ kv,
    float* __restrict__ out)
{
    int n = blockIdx.x * 4 + (threadIdx.x >> 6);
    int lane = threadIdx.x & 63;
    int cnt = cnt_in[n];
    int m = min(cnt, CAP);
    const int* b = bucket + ((size_t)n << 6);

    float2 q2 = *(const float2*)(Q + ((size_t)n << 7) + (lane << 1));
    float ax = 0.f, ay = 0.f, zacc = 0.f;

    int i = 0;
    for (; i + 4 <= m; i += 4) {
        int s0 = b[i], s1 = b[i + 1], s2 = b[i + 2], s3 = b[i + 3];
        uint2 p0 = *(const uint2*)(kv + ((size_t)s0 << 7) + (lane << 1));
        uint2 p1 = *(const uint2*)(kv + ((size_t)s1 << 7) + (lane << 1));
        uint2 p2 = *(const uint2*)(kv + ((size_t)s2 << 7) + (lane << 1));
        uint2 p3 = *(const uint2*)(kv + ((size_t)s3 << 7) + (lane << 1));
        attn_step(p0, q2.x, q2.y, ax, ay, zacc);
        attn_step(p1, q2.x, q2.y, ax, ay, zacc);
        attn_step(p2, q2.x, q2.y, ax, ay, zacc);
        attn_step(p3, q2.x, q2.y, ax, ay, zacc);
    }
    for (; i < m; ++i) {
        int s = b[i];
        uint2 p = *(const uint2*)(kv + ((size_t)s << 7) + (lane << 1));
        attn_step(p, q2.x, q2.y, ax, ay, zacc);
    }
    if (cnt > CAP) {                       // statistically never; correctness net
        int on = min(*ovf_n, OVF_CAP);
        for (int j = 0; j < on; ++j) {
            int2 pr = ovf[j];
            if (pr.x == n) {
                uint2 p = *(const uint2*)(kv + ((size_t)pr.y << 7) + (lane << 1));
                attn_step(p, q2.x, q2.y, ax, ay, zacc);
            }
        }
    }

    float inv = 1.0f / (zacc + 1e-6f);
    float2 o; o.x = ax * inv; o.y = ay * inv;
    *(float2*)(out + ((size_t)n << 7) + (lane << 1)) = o;
}

extern "C" void kernel_launch(void* const* d_in, const int* in_sizes, int n_in,
                              void* d_out, int out_size, void* d_ws, size_t ws_size,
                              hipStream_t stream) {
    const float* h   = (const float*)d_in[0];
    const float* WQ  = (const float*)d_in[1];
    const float* bQ  = (const float*)d_in[2];
    const float* WK  = (const float*)d_in[3];
    const float* bK  = (const float*)d_in[4];
    const float* WV  = (const float*)d_in[5];
    const float* bV  = (const float*)d_in[6];
    const int*   src = (const int*)d_in[7];
    const int*   dst = (const int*)d_in[8];
    float* out = (float*)d_out;
    float* ws  = (float*)d_ws;
    int*   wsi = (int*)d_ws;

    int*   cnt_out = wsi + O_CNTO;
    int*   cnt_in  = wsi + O_CNTI;
    int*   ovf_n   = wsi + O_OVFN;
    int2*  ovf     = (int2*)(wsi + O_OVF);
    int*   bucket  = wsi + O_BUCKET;
    uint*  hb      = (uint*)(ws + O_HB);
    float* agg     = ws + O_AGG;     // becomes Q in-place
    uint*  kv      = (uint*)(ws + O_KV);

    // zero cnt_out, cnt_in, ovf_n in one shot (contiguous)
    hipMemsetAsync(wsi, 0, (2 * N_NODES + 2) * sizeof(int), stream);

    k_build<<<N_EDGES / 256, 256, 0, stream>>>(src, dst, cnt_out, cnt_in,
                                               bucket, ovf_n, ovf);
    k_hb<<<(N_NODES * 64 + 255) / 256, 256, 0, stream>>>(h, cnt_out, hb);

    k_agg<<<N_NODES / 4, 256, 0, stream>>>(cnt_in, bucket, ovf_n, ovf, hb, agg);

    dim3 g_kv((N_NODES + 31) / 32, 2, 2);
    k_kv<<<g_kv, 128, 0, stream>>>(agg, WK, bK, WV, bV, kv);
    k_q_inplace<<<(N_NODES + 31) / 32, 256, 0, stream>>>(agg, WQ, bQ);

    k_attn<<<N_NODES / 4, 256, 0, stream>>>(cnt_in, bucket, ovf_n, ovf,
                                            agg, kv, out);
}

// Round 7
// 474.439 us; speedup vs baseline: 1.5443x; 1.1809x over previous
//
#include <hip/hip_runtime.h>

#define N_NODES 50000
#define N_EDGES 1600000
#define CAP 64            // bucket capacity per node; Poisson(32) tail @64 ~ 1e-7
#define OVF_CAP 8192

// Workspace element offsets (4-byte units). Peak ~90.2 MB.
#define O_CNTO   0         // int[50000]  out-degree
#define O_CNTI   50000     // int[50000]  in-degree (also bucket fill)
#define O_OVFN   100000    // int[1]      overflow count
#define O_OVF    100002    // int2[8192]  overflow (dst,src) pairs
#define O_BUCKET 120000    // int[50000*64] src per slot
#define O_HB     3320000   // uint[3.2M]  bf16x2 h*norm_out
#define O_AGGB   6520000   // uint[3.2M]  bf16x2 agg rows (256 B/node)
#define O_WT     9720000   // uint[24576] bf16 W^T for Q,K,V: [3][128 n][64 k-pairs]
#define O_Q      9750000   // f32[6.4M]   Q
#define O_KV     16150000  // uint[6.4M]  interleaved bf16 K/V rows (512 B/node)

typedef unsigned int uint;
typedef __attribute__((ext_vector_type(8))) short short8;
typedef __attribute__((ext_vector_type(4))) float floatx4;

union U16 { uint4 u; short8 s; };

__device__ __forceinline__ uint f2bf2(float a, float b) {
    uint ua = __float_as_uint(a); ua = (ua + 0x7fffu + ((ua >> 16) & 1u)) >> 16;
    uint ub = __float_as_uint(b); ub = (ub + 0x7fffu + ((ub >> 16) & 1u)) >> 16;
    return ua | (ub << 16);
}

// One-pass build: out-degree histogram + dst-buckets (with overflow safety net).
__global__ __launch_bounds__(256) void k_build(const int* __restrict__ src,
                                               const int* __restrict__ dst,
                                               int* cnt_out, int* cnt_in,
                                               int* __restrict__ bucket,
                                               int* ovf_n, int2* __restrict__ ovf) {
    int e = blockIdx.x * 256 + threadIdx.x;
    if (e < N_EDGES) {
        int s = src[e], d = dst[e];
        atomicAdd(&cnt_out[s], 1);
        int pos = atomicAdd(&cnt_in[d], 1);
        if (pos < CAP) {
            bucket[(d << 6) + pos] = s;
        } else {
            int o = atomicAdd(ovf_n, 1);
            if (o < OVF_CAP) ovf[o] = make_int2(d, s);
        }
    }
}

// W^T cast: wt[y][n][k2] = bf16x2(W_y[2k2][n], W_y[2k2+1][n])
__global__ __launch_bounds__(256) void k_wt(const float* __restrict__ WQ,
                                            const float* __restrict__ WK,
                                            const float* __restrict__ WV,
                                            uint* __restrict__ wt) {
    int idx = blockIdx.x * 256 + threadIdx.x;   // [0, 3*8192)
    if (idx < 3 * 8192) {
        int y = idx >> 13;
        int rem = idx & 8191;
        int k2 = rem >> 7;          // 0..63
        int n  = rem & 127;         // coalesced reads
        const float* W = (y == 0) ? WQ : (y == 1) ? WK : WV;
        float a = W[(2 * k2) * 128 + n];
        float b = W[(2 * k2 + 1) * 128 + n];
        wt[(y << 13) + (n << 6) + k2] = f2bf2(a, b);
    }
}

// hb[n][j] = bf16(h[n][j] * rsqrt(max(deg_out,1)))
__global__ __launch_bounds__(256) void k_hb(const float* __restrict__ h,
                                            const int* __restrict__ cnt_out,
                                            uint* __restrict__ hb) {
    int idx = blockIdx.x * 256 + threadIdx.x;   // [0, N*64)
    if (idx < N_NODES * 64) {
        int n = idx >> 6;
        float no = rsqrtf(fmaxf((float)cnt_out[n], 1.0f));
        float2 hv = *(const float2*)(h + ((size_t)idx << 1));
        hb[idx] = f2bf2(hv.x * no, hv.y * no);
    }
}

// aggb[n] = bf16( rsqrt(max(deg_in,1)) * sum_{slots of n} hb[s] )
__global__ __launch_bounds__(256) void k_agg(
    const int* __restrict__ cnt_in, const int* __restrict__ bucket,
    const int* __restrict__ ovf_n, const int2* __restrict__ ovf,
    const uint* __restrict__ hb, uint* __restrict__ aggb)
{
    int n = blockIdx.x * 4 + (threadIdx.x >> 6);
    int lane = threadIdx.x & 63;
    int cnt = cnt_in[n];
    int m = min(cnt, CAP);
    const int* b = bucket + ((size_t)n << 6);
    float ax = 0.f, ay = 0.f;
    int i = 0;
    for (; i + 4 <= m; i += 4) {
        int s0 = b[i], s1 = b[i + 1], s2 = b[i + 2], s3 = b[i + 3];
        uint u0 = hb[((size_t)s0 << 6) + lane];
        uint u1 = hb[((size_t)s1 << 6) + lane];
        uint u2 = hb[((size_t)s2 << 6) + lane];
        uint u3 = hb[((size_t)s3 << 6) + lane];
        ax += __uint_as_float(u0 << 16) + __uint_as_float(u1 << 16)
            + __uint_as_float(u2 << 16) + __uint_as_float(u3 << 16);
        ay += __uint_as_float(u0 & 0xffff0000u) + __uint_as_float(u1 & 0xffff0000u)
            + __uint_as_float(u2 & 0xffff0000u) + __uint_as_float(u3 & 0xffff0000u);
    }
    for (; i < m; ++i) {
        int s = b[i];
        uint u = hb[((size_t)s << 6) + lane];
        ax += __uint_as_float(u << 16);
        ay += __uint_as_float(u & 0xffff0000u);
    }
    if (cnt > CAP) {                       // statistically never; correctness net
        int on = min(*ovf_n, OVF_CAP);
        for (int j = 0; j < on; ++j) {
            int2 p = ovf[j];
            if (p.x == n) {
                uint u = hb[((size_t)p.y << 6) + lane];
                ax += __uint_as_float(u << 16);
                ay += __uint_as_float(u & 0xffff0000u);
            }
        }
    }
    float ni = rsqrtf(fmaxf((float)cnt, 1.0f));
    aggb[((size_t)n << 6) + lane] = f2bf2(ax * ni, ay * ni);
}

// Fused QKV projection via bf16 MFMA. grid (391, 3): y=0 Q(fp32), y=1 K, y=2 V.
// Block 256 = 4 waves; each wave computes 32 rows x 128 cols.
__global__ __launch_bounds__(256) void k_qkv(
    const uint* __restrict__ aggb, const uint* __restrict__ wt,
    const float* __restrict__ bQ, const float* __restrict__ bK,
    const float* __restrict__ bV,
    float* __restrict__ Q, uint* __restrict__ kv)
{
    const int y = blockIdx.y;
    const int row0 = blockIdx.x * 128;
    const float* bias = (y == 0) ? bQ : (y == 1) ? bK : bV;

    __shared__ uint sA[128 * 68];   // A tile, row stride 68 uints (pad: 2-way banks)

    const int t = threadIdx.x;
    for (int idx = t; idx < 128 * 16; idx += 256) {
        int r = idx >> 4, c4 = (idx & 15) << 2;
        int row = row0 + r;
        uint4 v = make_uint4(0u, 0u, 0u, 0u);
        if (row < N_NODES) v = *(const uint4*)(aggb + ((size_t)row << 6) + c4);
        *(uint4*)(&sA[r * 68 + c4]) = v;
    }
    __syncthreads();

    const int wave = t >> 6;
    const int lane = t & 63;
    const int mrow = lane & 15;     // m (A) / n (B) / col (C)
    const int kq   = lane >> 4;     // 0..3
    const int mbase = wave * 32;
    const uint* wty = wt + (y << 13);

    floatx4 acc[2][8];
    for (int a = 0; a < 2; ++a)
        for (int b = 0; b < 8; ++b)
            acc[a][b] = (floatx4){0.f, 0.f, 0.f, 0.f};

    for (int kc = 0; kc < 128; kc += 32) {
        int koff = (kc >> 1) + (kq << 2);    // uint offset within a row
        short8 afr[2], bfr[8];
        for (int mt = 0; mt < 2; ++mt) {
            U16 u; u.u = *(const uint4*)(&sA[(mbase + mt * 16 + mrow) * 68 + koff]);
            afr[mt] = u.s;
        }
        for (int nt = 0; nt < 8; ++nt) {
            U16 u; u.u = *(const uint4*)(wty + ((nt * 16 + mrow) << 6) + koff);
            bfr[nt] = u.s;
        }
        for (int mt = 0; mt < 2; ++mt)
            for (int nt = 0; nt < 8; ++nt)
                acc[mt][nt] = __builtin_amdgcn_mfma_f32_16x16x32_bf16(
                    afr[mt], bfr[nt], acc[mt][nt], 0, 0, 0);
    }

    // C/D: col = lane&15 (= mrow), row = kq*4 + reg
    if (y == 0) {
        for (int mt = 0; mt < 2; ++mt) {
            int rbase = row0 + mbase + mt * 16 + kq * 4;
            for (int nt = 0; nt < 8; ++nt) {
                int c = nt * 16 + mrow;
                float bv = bias[c];
                for (int r = 0; r < 4; ++r) {
                    int row = rbase + r;
                    if (row < N_NODES)
                        Q[((size_t)row << 7) + c] = fmaxf(acc[mt][nt][r] + bv, 0.f);
                }
            }
        }
    } else {
        const int vo = (y == 2) ? 1 : 0;
        for (int mt = 0; mt < 2; ++mt) {
            int rbase = row0 + mbase + mt * 16 + kq * 4;
            for (int nt = 0; nt < 8; ++nt) {
                int c = nt * 16 + mrow;
                float bv = bias[c];
                for (int r = 0; r < 4; ++r) {
                    float v = fmaxf(acc[mt][nt][r] + bv, 0.f);
                    float pv = __shfl_xor(v, 1);
                    int row = rbase + r;
                    if (((lane & 1) == 0) && row < N_NODES)
                        kv[((size_t)row << 7) + c + vo] = f2bf2(v, pv);
                }
            }
        }
    }
}

__device__ __forceinline__ void attn_step(uint2 kvp, float qx, float qy,
                                          float& ax, float& ay, float& zacc) {
    float p = __uint_as_float(kvp.x << 16) * qx
            + __uint_as_float(kvp.x & 0xffff0000u) * qy;
    p += __shfl_xor(p, 1);
    p += __shfl_xor(p, 2);
    p += __shfl_xor(p, 4);
    float sc = __expf(fminf(fmaxf(p * 0.25f, -10.f), 10.f));
    ax += __uint_as_float(kvp.y << 16) * sc;
    ay += __uint_as_float(kvp.y & 0xffff0000u) * sc;
    zacc += sc;
}

// Attention gather over interleaved KV from buckets; one wave per node; unroll x4
__global__ __launch_bounds__(256) void k_attn(
    const int* __restrict__ cnt_in, const int* __restrict__ bucket,
    const int* __restrict__ ovf_n, const int2* __restrict__ ovf,
    const float* __restrict__ Q, const uint* __restrict__ kv,
    float* __restrict__ out)
{
    int n = blockIdx.x * 4 + (threadIdx.x >> 6);
    int lane = threadIdx.x & 63;
    int cnt = cnt_in[n];
    int m = min(cnt, CAP);
    const int* b = bucket + ((size_t)n << 6);

    float2 q2 = *(const float2*)(Q + ((size_t)n << 7) + (lane << 1));
    float ax = 0.f, ay = 0.f, zacc = 0.f;

    int i = 0;
    for (; i + 4 <= m; i += 4) {
        int s0 = b[i], s1 = b[i + 1], s2 = b[i + 2], s3 = b[i + 3];
        uint2 p0 = *(const uint2*)(kv + ((size_t)s0 << 7) + (lane << 1));
        uint2 p1 = *(const uint2*)(kv + ((size_t)s1 << 7) + (lane << 1));
        uint2 p2 = *(const uint2*)(kv + ((size_t)s2 << 7) + (lane << 1));
        uint2 p3 = *(const uint2*)(kv + ((size_t)s3 << 7) + (lane << 1));
        attn_step(p0, q2.x, q2.y, ax, ay, zacc);
        attn_step(p1, q2.x, q2.y, ax, ay, zacc);
        attn_step(p2, q2.x, q2.y, ax, ay, zacc);
        attn_step(p3, q2.x, q2.y, ax, ay, zacc);
    }
    for (; i < m; ++i) {
        int s = b[i];
        uint2 p = *(const uint2*)(kv + ((size_t)s << 7) + (lane << 1));
        attn_step(p, q2.x, q2.y, ax, ay, zacc);
    }
    if (cnt > CAP) {                       // statistically never; correctness net
        int on = min(*ovf_n, OVF_CAP);
        for (int j = 0; j < on; ++j) {
            int2 pr = ovf[j];
            if (pr.x == n) {
                uint2 p = *(const uint2*)(kv + ((size_t)pr.y << 7) + (lane << 1));
                attn_step(p, q2.x, q2.y, ax, ay, zacc);
            }
        }
    }

    float inv = 1.0f / (zacc + 1e-6f);
    float2 o; o.x = ax * inv; o.y = ay * inv;
    *(float2*)(out + ((size_t)n << 7) + (lane << 1)) = o;
}

extern "C" void kernel_launch(void* const* d_in, const int* in_sizes, int n_in,
                              void* d_out, int out_size, void* d_ws, size_t ws_size,
                              hipStream_t stream) {
    const float* h   = (const float*)d_in[0];
    const float* WQ  = (const float*)d_in[1];
    const float* bQ  = (const float*)d_in[2];
    const float* WK  = (const float*)d_in[3];
    const float* bK  = (const float*)d_in[4];
    const float* WV  = (const float*)d_in[5];
    const float* bV  = (const float*)d_in[6];
    const int*   src = (const int*)d_in[7];
    const int*   dst = (const int*)d_in[8];
    float* out = (float*)d_out;
    float* ws  = (float*)d_ws;
    int*   wsi = (int*)d_ws;

    int*   cnt_out = wsi + O_CNTO;
    int*   cnt_in  = wsi + O_CNTI;
    int*   ovf_n   = wsi + O_OVFN;
    int2*  ovf     = (int2*)(wsi + O_OVF);
    int*   bucket  = wsi + O_BUCKET;
    uint*  hb      = (uint*)(ws + O_HB);
    uint*  aggb    = (uint*)(ws + O_AGGB);
    uint*  wt      = (uint*)(ws + O_WT);
    float* Q       = ws + O_Q;
    uint*  kv      = (uint*)(ws + O_KV);

    hipMemsetAsync(wsi, 0, (2 * N_NODES + 2) * sizeof(int), stream);

    k_wt<<<(3 * 8192 + 255) / 256, 256, 0, stream>>>(WQ, WK, WV, wt);
    k_build<<<N_EDGES / 256, 256, 0, stream>>>(src, dst, cnt_out, cnt_in,
                                               bucket, ovf_n, ovf);
    k_hb<<<(N_NODES * 64 + 255) / 256, 256, 0, stream>>>(h, cnt_out, hb);

    k_agg<<<N_NODES / 4, 256, 0, stream>>>(cnt_in, bucket, ovf_n, ovf, hb, aggb);

    dim3 g_qkv((N_NODES + 127) / 128, 3);
    k_qkv<<<g_qkv, 256, 0, stream>>>(aggb, wt, bQ, bK, bV, Q, kv);

    k_attn<<<N_NODES / 4, 256, 0, stream>>>(cnt_in, bucket, ovf_n, ovf,
                                            Q, kv, out);
}